// Round 13
// baseline (851.733 us; speedup 1.0000x reference)
//
#include <hip/hip_runtime.h>
#include <hip/hip_bf16.h>

#define NB   64     // batch
#define NS   128    // seq len
#define ND   256    // embed dim
#define NU   512    // hidden units
#define N3   1536   // 3*NU

typedef __attribute__((ext_vector_type(4))) float  f32x4;
typedef __attribute__((ext_vector_type(8))) short  s16x8;
typedef unsigned long long u64;
typedef unsigned int       u32;
typedef unsigned short     u16;

__device__ __forceinline__ u16 f2bf(float v) {
  unsigned u = __builtin_bit_cast(unsigned, v);
  u += 0x7fffu + ((u >> 16) & 1u);          // round-to-nearest-even
  return (u16)(u >> 16);
}

// -------- init: h ping-pong slot0 = hidden (f32 + bf16 copy) -------------------
__global__ __launch_bounds__(512) void hinit_kernel(const float* __restrict__ hidden,
                                                    float* __restrict__ hf,
                                                    u16* __restrict__ hb) {
  const int tid = blockIdx.x * 512 + threadIdx.x;    // 64*512 = 32768
  const float v = hidden[tid];
  hf[tid] = v;
  hb[tid] = f2bf(v);
}

// -------- Rbf[c][k] = bf16(R[k][c]) : tiled LDS transpose ----------------------
__global__ __launch_bounds__(256) void rtrans_kernel(const float* __restrict__ R,
                                                     u16* __restrict__ Rbf) {
  __shared__ float ld[64][65];
  const int c0 = blockIdx.x * 64;      // 24 tiles
  const int k0 = blockIdx.y * 64;      // 8 tiles
  const int tx = threadIdx.x & 63, ty = threadIdx.x >> 6;   // ty 0..3
  #pragma unroll
  for (int r = 0; r < 16; ++r) {
    const int k = ty + r * 4;
    ld[k][tx] = R[(size_t)(k0 + k) * N3 + c0 + tx];
  }
  __syncthreads();
  #pragma unroll
  for (int r = 0; r < 16; ++r) {
    const int c = ty + r * 4;
    Rbf[(size_t)(c0 + c) * NU + k0 + tx] = f2bf(ld[tx][c]);
  }
}

// -------- phase 1: xp = gather(emb,x) @ W + b_in  (f32 SIMT, unchanged) --------
__global__ __launch_bounds__(256) void xproj_kernel(
    const int* __restrict__ x, const float* __restrict__ emb,
    const float* __restrict__ W, const float* __restrict__ bias,
    float* __restrict__ xp) {
  __shared__ float As[32][68];
  __shared__ float Bs[32][68];
  __shared__ int tok[64];
  const int tid = threadIdx.x;
  const int m0 = blockIdx.y * 64;
  const int n0 = blockIdx.x * 64;
  if (tid < 64) tok[tid] = x[m0 + tid];
  __syncthreads();
  const int tx = tid & 15, ty = tid >> 4;
  float acc[4][4] = {};
  for (int k0 = 0; k0 < ND; k0 += 32) {
    {
      const int m = tid & 63, kq = tid >> 6;
      const float* src = emb + (size_t)tok[m] * ND + k0 + kq * 8;
      const float4 v0 = *(const float4*)(src);
      const float4 v1 = *(const float4*)(src + 4);
      As[kq*8+0][m] = v0.x; As[kq*8+1][m] = v0.y;
      As[kq*8+2][m] = v0.z; As[kq*8+3][m] = v0.w;
      As[kq*8+4][m] = v1.x; As[kq*8+5][m] = v1.y;
      As[kq*8+6][m] = v1.z; As[kq*8+7][m] = v1.w;
    }
    {
      const int n = (tid & 15) * 4, k = tid >> 4;
      *(float4*)&Bs[k][n]    = *(const float4*)&W[(size_t)(k0 + k) * N3 + n0 + n];
      *(float4*)&Bs[k+16][n] = *(const float4*)&W[(size_t)(k0 + k + 16) * N3 + n0 + n];
    }
    __syncthreads();
    #pragma unroll
    for (int kk = 0; kk < 32; ++kk) {
      const float4 b4 = *(const float4*)&Bs[kk][tx * 4];
      float a[4];
      #pragma unroll
      for (int i = 0; i < 4; ++i) a[i] = As[kk][ty * 4 + i];
      #pragma unroll
      for (int i = 0; i < 4; ++i) {
        acc[i][0] += a[i] * b4.x;
        acc[i][1] += a[i] * b4.y;
        acc[i][2] += a[i] * b4.z;
        acc[i][3] += a[i] * b4.w;
      }
    }
    __syncthreads();
  }
  #pragma unroll
  for (int i = 0; i < 4; ++i) {
    const size_t row = (size_t)(m0 + ty * 4 + i) * N3 + n0 + tx * 4;
    float4 o;
    o.x = acc[i][0] + bias[n0 + tx*4 + 0];
    o.y = acc[i][1] + bias[n0 + tx*4 + 1];
    o.z = acc[i][2] + bias[n0 + tx*4 + 2];
    o.w = acc[i][3] + bias[n0 + tx*4 + 3];
    *(float4*)&xp[row] = o;
  }
}

// -------- phase 2: ONE GRU timestep per kernel launch --------------------------
// The kernel boundary is the producer->consumer barrier (CP-managed dispatch +
// coherence): no flags, no sentinels, no atomics — plain loads/stores only.
// 64 blocks = 4 batch-tiles (16 rows) x 16 unit-blocks (32 units, 96 gate-cols).
// B-fragments read directly from the pre-transposed Rbf (L2-hot, 96KB/block).
// h carried in f32 (exact R4 numerics); bf16 copy feeds the MFMA A-fragments.
__global__ __launch_bounds__(128) void gru_step_kernel(
    const float* __restrict__ xp, const u16* __restrict__ Rbf,
    const float* __restrict__ bias,
    const u16* __restrict__ hi16, const float* __restrict__ hi32,
    u16* __restrict__ ho16, float* __restrict__ ho32,
    float* __restrict__ out, int t) {
  const int bid = blockIdx.x;
  const int g   = bid >> 4;          // batch tile 0..3
  const int u0  = (bid & 15) * 32;   // unit base
  const int lane = threadIdx.x & 63;
  const int wv   = threadIdx.x >> 6;

  const int ar  = lane & 15;             // A row (batch within tile)
  const int kg  = lane >> 4;             // k-group
  const int cu  = lane & 15;             // unit within wave slice
  const int myu = u0 + (wv << 4) + cu;   // my global unit
  const int drow = kg << 2;              // batch base for D rows

  // xp loads (independent; issue first)
  float xg0[4], xg1[4], xg2[4];
  #pragma unroll
  for (int i = 0; i < 4; ++i) {
    const float* q = xp + ((size_t)(((g << 4) + drow + i) * NS) + t) * N3 + myu;
    xg0[i] = q[0]; xg1[i] = q[512]; xg2[i] = q[1024];
  }
  // previous h (f32 master) for the update term
  float hp[4];
  #pragma unroll
  for (int i = 0; i < 4; ++i)
    hp[i] = hi32[(size_t)((g << 4) + drow + i) * NU + myu];

  // A-fragments: 16 x 16B from bf16 h row
  const u16* ha = hi16 + ((size_t)(g << 4) + ar) * NU + (kg << 3);
  s16x8 af[16];
  #pragma unroll
  for (int ks = 0; ks < 16; ++ks)
    af[ks] = *(const s16x8*)(ha + (ks << 5));

  // B-fragment bases: Rbf[c][k], c = gate*512 + myu
  const u16* b0 = Rbf + ((size_t)(       myu) << 9) + (kg << 3);
  const u16* b1 = Rbf + ((size_t)( 512 + myu) << 9) + (kg << 3);
  const u16* b2 = Rbf + ((size_t)(1024 + myu) << 9) + (kg << 3);

  f32x4 a0 = {0.f,0.f,0.f,0.f}, a1 = a0, a2 = a0;
  #pragma unroll
  for (int ks = 0; ks < 16; ++ks) {
    a0 = __builtin_amdgcn_mfma_f32_16x16x32_bf16(af[ks], *(const s16x8*)(b0 + (ks << 5)), a0, 0,0,0);
    a1 = __builtin_amdgcn_mfma_f32_16x16x32_bf16(af[ks], *(const s16x8*)(b1 + (ks << 5)), a1, 0,0,0);
    a2 = __builtin_amdgcn_mfma_f32_16x16x32_bf16(af[ks], *(const s16x8*)(b2 + (ks << 5)), a2, 0,0,0);
  }

  const float bz = bias[N3 + myu];
  const float br = bias[N3 + 512 + myu];
  const float bh = bias[N3 + 1024 + myu];

  #pragma unroll
  for (int i = 0; i < 4; ++i) {
    const float z = 1.f / (1.f + __expf(-(xg0[i] + a0[i] + bz)));
    const float r = 1.f / (1.f + __expf(-(xg1[i] + a1[i] + br)));
    const float e = __expf(2.f * (xg2[i] + r * (a2[i] + bh)));
    const float hh = (e - 1.f) / (e + 1.f);        // tanh
    const float hn = z * hp[i] + (1.f - z) * hh;
    const size_t b = (size_t)(g << 4) + drow + i;
    out[(b * NS + t) * NU + myu] = hn;
    if (t < NS - 1) {
      ho32[b * NU + myu] = hn;
      ho16[b * NU + myu] = f2bf(hn);
    } else {
      out[(size_t)NB * NS * NU + b * NU + myu] = hn;   // final state tail
    }
  }
}

extern "C" void kernel_launch(void* const* d_in, const int* in_sizes, int n_in,
                              void* d_out, int out_size, void* d_ws, size_t ws_size,
                              hipStream_t stream) {
  const int*   x      = (const int*)d_in[0];
  const float* hidden = (const float*)d_in[1];
  const float* emb    = (const float*)d_in[2];
  const float* W      = (const float*)d_in[3];
  const float* R      = (const float*)d_in[4];
  const float* bias   = (const float*)d_in[5];
  float* out = (float*)d_out;

  char* ws = (char*)d_ws;
  float* xp   = (float*)ws;                              // 50,331,648 B
  u16*   Rbf  = (u16*)(ws + 50331648);                   //  1,572,864 B
  u16*   hb16 = (u16*)(ws + 50331648 + 1572864);         //  2 x 65,536 B
  float* hf32 = (float*)(ws + 50331648 + 1572864 + 131072); // 2 x 262,144 B

  hinit_kernel<<<NB, NU, 0, stream>>>(hidden, hf32, hb16);
  dim3 gT(N3 / 64, NU / 64);
  rtrans_kernel<<<gT, 256, 0, stream>>>(R, Rbf);
  dim3 gA(N3 / 64, (NB * NS) / 64);
  xproj_kernel<<<gA, 256, 0, stream>>>(x, emb, W, bias, xp);

  for (int t = 0; t < NS; ++t) {
    const u16*   hi16 = hb16 + (t & 1) * (NB * NU);
    u16*         ho16 = hb16 + ((t + 1) & 1) * (NB * NU);
    const float* hi32 = hf32 + (t & 1) * (NB * NU);
    float*       ho32 = hf32 + ((t + 1) & 1) * (NB * NU);
    gru_step_kernel<<<64, 128, 0, stream>>>(xp, Rbf, bias, hi16, hi32,
                                            ho16, ho32, out, t);
  }
}